// Round 1
// baseline (2287.308 us; speedup 1.0000x reference)
//
#include <hip/hip_runtime.h>
#include <hip/hip_bf16.h>

// Sizes (fixed by the reference)
#define BB 32
#define RR 6
#define SS 512
#define DD 256
#define HH 64
#define FF 256

// ---------------- block reduction helpers (256-thread blocks, wave=64) ----------------
__device__ __forceinline__ float block_sum256(float v, float* red) {
    #pragma unroll
    for (int off = 32; off > 0; off >>= 1) v += __shfl_down(v, off, 64);
    int wid = threadIdx.x >> 6, lane = threadIdx.x & 63;
    if (lane == 0) red[wid] = v;
    __syncthreads();
    if (threadIdx.x == 0) {
        float s = red[0] + red[1] + red[2] + red[3];
        red[0] = s;
    }
    __syncthreads();
    float r = red[0];
    __syncthreads();            // make red reusable
    return r;
}

__device__ __forceinline__ float block_max256(float v, float* red) {
    #pragma unroll
    for (int off = 32; off > 0; off >>= 1) v = fmaxf(v, __shfl_down(v, off, 64));
    int wid = threadIdx.x >> 6, lane = threadIdx.x & 63;
    if (lane == 0) red[wid] = v;
    __syncthreads();
    if (threadIdx.x == 0) {
        float s = fmaxf(fmaxf(red[0], red[1]), fmaxf(red[2], red[3]));
        red[0] = s;
    }
    __syncthreads();
    float r = red[0];
    __syncthreads();
    return r;
}

// ---------------- Kernel A: Q,K,V = x @ Wq/Wk/Wv per relation ----------------
// grid = B*R*S blocks, 192 threads: thread (which, h) computes one output.
__global__ __launch_bounds__(192) void qkv_kernel(
        const float* __restrict__ x,
        const float* __restrict__ Wq, const float* __restrict__ Wk, const float* __restrict__ Wv,
        float* __restrict__ q, float* __restrict__ k, float* __restrict__ v) {
    int row = blockIdx.x;              // (b*R + r)*S + s
    int s_i = row & (SS - 1);
    int br  = row >> 9;                // b*R + r
    int b = br / RR, r = br % RR;

    __shared__ float xs[DD];
    int tid = threadIdx.x;
    const float* xrow = x + ((size_t)b * SS + s_i) * DD;
    for (int i = tid; i < DD; i += 192) xs[i] = xrow[i];
    __syncthreads();

    int which = tid >> 6, h = tid & 63;
    const float* W = (which == 0 ? Wq : which == 1 ? Wk : Wv) + (size_t)r * DD * HH;
    float acc = 0.f;
    #pragma unroll 8
    for (int d = 0; d < DD; ++d) acc += xs[d] * W[d * HH + h];
    float* out = (which == 0 ? q : which == 1 ? k : v);
    out[(size_t)row * HH + h] = acc;
}

// ---------------- Kernel B: masked attention, one (b,r,s) row per block ----------------
__global__ __launch_bounds__(256) void attn_kernel(
        const float* __restrict__ q, const float* __restrict__ k, const float* __restrict__ v,
        const int* __restrict__ mask, float* __restrict__ ctx) {
    int row = blockIdx.x;              // (b*R + r)*S + s
    int br  = row >> 9;
    const float* kb   = k + (size_t)br * SS * HH;
    const float* vb   = v + (size_t)br * SS * HH;
    const float* qrow = q + (size_t)row * HH;
    const int*   mrow = mask + (size_t)row * SS;   // mask[b,r,s,:] — same row index

    __shared__ float qs[HH];
    __shared__ float kt[128 * 65];     // 128 K-rows, pad 65: lanes hit banks (t+h)%32 → 2-way (free)
    __shared__ float sc[SS];
    __shared__ float red[4];
    __shared__ float pacc[4][HH];

    int tid = threadIdx.x;
    if (tid < HH) qs[tid] = qrow[tid];

    // scores, 128 t at a time with K staged in LDS
    for (int chunk = 0; chunk < SS; chunk += 128) {
        __syncthreads();               // kt reuse-safe + qs visible on first iter
        for (int i = tid; i < 128 * HH; i += 256) {
            int t = i >> 6, h = i & 63;
            kt[t * 65 + h] = kb[(size_t)chunk * HH + i];   // coalesced
        }
        __syncthreads();
        if (tid < 128) {
            const float* kr = &kt[tid * 65];
            float acc = 0.f;
            #pragma unroll
            for (int h = 0; h < HH; ++h) acc += qs[h] * kr[h];
            int t = chunk + tid;
            sc[t] = mrow[t] ? -1e9f : acc * 0.125f;        // SCALE = 1/8
        }
    }
    __syncthreads();

    // softmax over 512 (each thread owns 2 entries)
    float mymax = fmaxf(sc[tid], sc[tid + 256]);
    float mx = block_max256(mymax, red);
    float e0 = __expf(sc[tid] - mx);
    float e1 = __expf(sc[tid + 256] - mx);
    float sum = block_sum256(e0 + e1, red);
    float inv = 1.f / sum;
    // post-softmax zeroing of masked entries (matches reference; handles all-masked rows)
    sc[tid]       = mrow[tid]       ? 0.f : e0 * inv;
    sc[tid + 256] = mrow[tid + 256] ? 0.f : e1 * inv;
    __syncthreads();

    // ctx = attn @ V : thread (h, part) sums 128 t's
    int h = tid & 63, part = tid >> 6;
    float acc = 0.f;
    int t0 = part * 128;
    for (int t = t0; t < t0 + 128; ++t)
        acc += sc[t] * vb[(size_t)t * HH + h];             // coalesced in h
    pacc[part][h] = acc;
    __syncthreads();
    if (tid < HH) {
        float c = pacc[0][tid] + pacc[1][tid] + pacc[2][tid] + pacc[3][tid];
        ctx[(size_t)row * HH + tid] = c;
    }
}

// ---------------- Kernel C: branch proj + residual + LN, summed over 6 branches ----------------
// grid = B*S, 256 threads (thread = d)
__global__ __launch_bounds__(256) void proj_ln_kernel(
        const float* __restrict__ ctx, const float* __restrict__ Wfc,
        const float* __restrict__ x, float* __restrict__ srow) {
    int bs = blockIdx.x;               // b*S + s
    int b = bs >> 9, s_i = bs & (SS - 1);
    int tid = threadIdx.x;             // d

    __shared__ float cx[HH];
    __shared__ float red[4];

    float xv = x[(size_t)bs * DD + tid];
    float acc = 0.f;
    for (int r = 0; r < RR; ++r) {
        if (tid < HH)
            cx[tid] = ctx[(((size_t)b * RR + r) * SS + s_i) * HH + tid];
        __syncthreads();
        const float* W = Wfc + (size_t)r * HH * DD;
        float p = 0.f;
        #pragma unroll
        for (int h = 0; h < HH; ++h) p += cx[h] * W[h * DD + tid];   // coalesced in d
        p += xv;
        float mean = block_sum256(p, red) * (1.f / 256.f);
        float d0 = p - mean;
        float var = block_sum256(d0 * d0, red) * (1.f / 256.f);
        acc += d0 * rsqrtf(var + 1e-5f);
        __syncthreads();               // cx reuse-safe
    }
    srow[(size_t)bs * DD + tid] = acc;
}

// ---------------- Kernel D: FFN + residual + LN ----------------
__global__ __launch_bounds__(256) void ffn_kernel(
        const float* __restrict__ srow, const float* __restrict__ W1,
        const float* __restrict__ W2, float* __restrict__ out) {
    int bs = blockIdx.x;
    int tid = threadIdx.x;

    __shared__ float sr[DD];
    __shared__ float hr[FF];
    __shared__ float red[4];

    float sv = srow[(size_t)bs * DD + tid];
    sr[tid] = sv;
    __syncthreads();
    float a = 0.f;
    #pragma unroll 8
    for (int d = 0; d < DD; ++d) a += sr[d] * W1[d * FF + tid];
    hr[tid] = fmaxf(a, 0.f);
    __syncthreads();
    float o = 0.f;
    #pragma unroll 8
    for (int f = 0; f < FF; ++f) o += hr[f] * W2[f * DD + tid];
    o += sv;
    float mean = block_sum256(o, red) * (1.f / 256.f);
    float d0 = o - mean;
    float var = block_sum256(d0 * d0, red) * (1.f / 256.f);
    out[(size_t)bs * DD + tid] = d0 * rsqrtf(var + 1e-5f);
}

// ---------------- launch ----------------
extern "C" void kernel_launch(void* const* d_in, const int* in_sizes, int n_in,
                              void* d_out, int out_size, void* d_ws, size_t ws_size,
                              hipStream_t stream) {
    const float* x    = (const float*)d_in[0];
    const int*   mask = (const int*)  d_in[1];
    const float* Wq   = (const float*)d_in[2];
    const float* Wk   = (const float*)d_in[3];
    const float* Wv   = (const float*)d_in[4];
    const float* Wfc  = (const float*)d_in[5];
    const float* W1   = (const float*)d_in[6];
    const float* W2   = (const float*)d_in[7];
    float* out = (float*)d_out;

    float* ws = (float*)d_ws;
    const size_t QKV = (size_t)BB * RR * SS * HH;   // 6,291,456 floats
    float* q    = ws;
    float* k    = q + QKV;
    float* v    = k + QKV;
    float* ctx  = v + QKV;
    float* srow = ctx + QKV;                        // B*S*D floats

    const int nrows = BB * RR * SS;                 // 98304
    const int nbs   = BB * SS;                      // 16384

    qkv_kernel    <<<nrows, 192, 0, stream>>>(x, Wq, Wk, Wv, q, k, v);
    attn_kernel   <<<nrows, 256, 0, stream>>>(q, k, v, mask, ctx);
    proj_ln_kernel<<<nbs,   256, 0, stream>>>(ctx, Wfc, x, srow);
    ffn_kernel    <<<nbs,   256, 0, stream>>>(srow, W1, W2, out);
}

// Round 2
// 1104.611 us; speedup vs baseline: 2.0707x; 2.0707x over previous
//
#include <hip/hip_runtime.h>
#include <hip/hip_bf16.h>

// Sizes (fixed by the reference)
#define BB 32
#define RR 6
#define SS 512
#define DD 256
#define HH 64
#define FF 256

typedef short  short8 __attribute__((ext_vector_type(8)));
typedef float  f32x4  __attribute__((ext_vector_type(4)));
typedef unsigned short ushort_t;

// ---------------- block reduction helpers (256-thread blocks, wave=64) ----------------
__device__ __forceinline__ float block_sum256(float v, float* red) {
    #pragma unroll
    for (int off = 32; off > 0; off >>= 1) v += __shfl_down(v, off, 64);
    int wid = threadIdx.x >> 6, lane = threadIdx.x & 63;
    if (lane == 0) red[wid] = v;
    __syncthreads();
    if (threadIdx.x == 0) red[0] = red[0] + red[1] + red[2] + red[3];
    __syncthreads();
    float r = red[0];
    __syncthreads();
    return r;
}

// ---------------- Kernel A: Q,K,V = x @ Wq/Wk/Wv per relation (bf16 out) ----------------
__global__ __launch_bounds__(192) void qkv_kernel(
        const float* __restrict__ x,
        const float* __restrict__ Wq, const float* __restrict__ Wk, const float* __restrict__ Wv,
        __hip_bfloat16* __restrict__ q, __hip_bfloat16* __restrict__ k, __hip_bfloat16* __restrict__ v) {
    int row = blockIdx.x;              // (b*R + r)*S + s
    int s_i = row & (SS - 1);
    int br  = row >> 9;                // b*R + r
    int b = br / RR, r = br % RR;

    __shared__ float xs[DD];
    int tid = threadIdx.x;
    const float* xrow = x + ((size_t)b * SS + s_i) * DD;
    for (int i = tid; i < DD; i += 192) xs[i] = xrow[i];
    __syncthreads();

    int which = tid >> 6, h = tid & 63;
    const float* W = (which == 0 ? Wq : which == 1 ? Wk : Wv) + (size_t)r * DD * HH;
    float acc = 0.f;
    #pragma unroll 8
    for (int d = 0; d < DD; ++d) acc += xs[d] * W[d * HH + h];
    __hip_bfloat16* out = (which == 0 ? q : which == 1 ? k : v);
    out[(size_t)row * HH + h] = __float2bfloat16(acc);
}

// ---------------- Kernel B: flash MFMA attention ----------------
// grid = 192 br * 8 qtiles = 1536 blocks, 256 threads (4 waves, 16 q-rows each).
__global__ __launch_bounds__(256) void attn_mfma_kernel(
        const ushort_t* __restrict__ q, const ushort_t* __restrict__ k,
        const ushort_t* __restrict__ v, const int* __restrict__ mask,
        float* __restrict__ ctx) {
    // XCD-aware swizzle: 1536 = 8 XCD * 192; each XCD gets 24 consecutive br's
    int wg = blockIdx.x;
    int id = (wg & 7) * 192 + (wg >> 3);
    int br = id >> 3, qt = id & 7;

    __shared__ ushort_t K_lds[64 * 72];       // [t][h], pad 8 -> 2-way banks (free)
    __shared__ ushort_t VT_lds[64 * 72];      // [h][t], pad 8
    __shared__ ushort_t P_lds[4][16 * 72];    // per-wave [q][t], pad 8

    int tid = threadIdx.x;
    int wv = tid >> 6, l = tid & 63;
    int g = l >> 4, lc = l & 15;

    int q0 = qt * 64 + wv * 16;                       // first q-row of this wave
    const size_t base_kv = (size_t)br * SS * HH;      // element offset of K/V panel

    // Q fragments hoisted: A-layout lane l: row=lc, k=h=kk*32+g*8+i (16B contiguous)
    short8 qf[2];
    #pragma unroll
    for (int kk = 0; kk < 2; ++kk)
        qf[kk] = *(const short8*)(q + ((size_t)br * SS + q0 + lc) * HH + kk * 32 + g * 8);

    f32x4 O[4] = {{0,0,0,0},{0,0,0,0},{0,0,0,0},{0,0,0,0}};
    float mrun[4] = {-1e9f, -1e9f, -1e9f, -1e9f};
    float lrun[4] = {0.f, 0.f, 0.f, 0.f};

    const int* mb = mask + ((size_t)br * SS + q0) * SS;   // mask[b,r,q0+..,:]

    for (int t0 = 0; t0 < SS; t0 += 64) {
        __syncthreads();   // previous tile's LDS reads done
        // stage K tile [64][64] -> K_lds[t][h], 16B chunks, coalesced
        for (int c = tid; c < 512; c += 256) {
            int t = c >> 3, c8 = (c & 7) * 8;
            *(short8*)&K_lds[t * 72 + c8] =
                *(const short8*)(k + base_kv + (size_t)(t0 + t) * HH + c8);
        }
        // stage V^T: thread (h=tid&63, tseg=tid>>6) copies 16 t's (coalesced 2B loads)
        {
            int h = tid & 63, tseg = tid >> 6;
            #pragma unroll
            for (int j = 0; j < 16; ++j) {
                int t = tseg * 16 + j;
                VT_lds[h * 72 + t] = v[base_kv + (size_t)(t0 + t) * HH + h];
            }
        }
        __syncthreads();

        // ---- QK^T: S[tc] covers t = t0 + tc*16 + lc, q = q0 + 4g + reg
        f32x4 S[4];
        #pragma unroll
        for (int tc = 0; tc < 4; ++tc) {
            f32x4 c = {0, 0, 0, 0};
            #pragma unroll
            for (int kk = 0; kk < 2; ++kk) {
                short8 bf = *(const short8*)&K_lds[(tc * 16 + lc) * 72 + kk * 32 + g * 8];
                c = __builtin_amdgcn_mfma_f32_16x16x32_bf16(qf[kk], bf, c, 0, 0, 0);
            }
            S[tc] = c;
        }

        // ---- mask + scale (sentinel -1e9 exactly as reference pre-softmax)
        float tmax[4] = {-1e9f, -1e9f, -1e9f, -1e9f};
        #pragma unroll
        for (int tc = 0; tc < 4; ++tc)
            #pragma unroll
            for (int reg = 0; reg < 4; ++reg) {
                int qrow = 4 * g + reg;
                int mv = mb[(size_t)qrow * SS + t0 + tc * 16 + lc];
                float sv = mv ? -1e9f : S[tc][reg] * 0.125f;
                S[tc][reg] = sv;
                tmax[reg] = fmaxf(tmax[reg], sv);
            }
        // row-max across the 16 lanes holding this row
        #pragma unroll
        for (int reg = 0; reg < 4; ++reg) {
            float tm = tmax[reg];
            tm = fmaxf(tm, __shfl_xor(tm, 1, 64));
            tm = fmaxf(tm, __shfl_xor(tm, 2, 64));
            tm = fmaxf(tm, __shfl_xor(tm, 4, 64));
            tm = fmaxf(tm, __shfl_xor(tm, 8, 64));
            tmax[reg] = tm;
        }
        float psum[4];
        #pragma unroll
        for (int reg = 0; reg < 4; ++reg) {
            float mnew = fmaxf(mrun[reg], tmax[reg]);
            float corr = __expf(mrun[reg] - mnew);   // exp(0)=1 when both -1e9 (no NaN)
            mrun[reg] = mnew;
            lrun[reg] *= corr;
            O[0][reg] *= corr; O[1][reg] *= corr; O[2][reg] *= corr; O[3][reg] *= corr;
            psum[reg] = 0.f;
        }
        // p = exp(s - m), masked -> exactly 0 (reference post-softmax zeroing)
        ushort_t* Pw = P_lds[wv];
        #pragma unroll
        for (int tc = 0; tc < 4; ++tc)
            #pragma unroll
            for (int reg = 0; reg < 4; ++reg) {
                float sv = S[tc][reg];
                float p = (sv == -1e9f) ? 0.f : __expf(sv - mrun[reg]);
                psum[reg] += p;
                __hip_bfloat16 pb = __float2bfloat16(p);
                Pw[(4 * g + reg) * 72 + tc * 16 + lc] = __builtin_bit_cast(ushort_t, pb);
            }
        #pragma unroll
        for (int reg = 0; reg < 4; ++reg) {
            float ps = psum[reg];
            ps += __shfl_xor(ps, 1, 64);
            ps += __shfl_xor(ps, 2, 64);
            ps += __shfl_xor(ps, 4, 64);
            ps += __shfl_xor(ps, 8, 64);
            lrun[reg] += ps;
        }
        // wave-private P: drain LDS writes before re-reading cross-lane
        asm volatile("s_waitcnt lgkmcnt(0)" ::: "memory");

        // ---- PV: O[hb] += P[16q x 64t] * V[64t x 16h]
        #pragma unroll
        for (int ts = 0; ts < 2; ++ts) {
            short8 pa = *(const short8*)&Pw[lc * 72 + ts * 32 + g * 8];
            #pragma unroll
            for (int hb = 0; hb < 4; ++hb) {
                short8 vbf = *(const short8*)&VT_lds[(hb * 16 + lc) * 72 + ts * 32 + g * 8];
                O[hb] = __builtin_amdgcn_mfma_f32_16x16x32_bf16(pa, vbf, O[hb], 0, 0, 0);
            }
        }
    }

    // epilogue: ctx = O / l  (l==0 -> all-masked row -> 0)
    float* cb = ctx + ((size_t)br * SS + q0) * HH;
    #pragma unroll
    for (int reg = 0; reg < 4; ++reg) {
        float inv = lrun[reg] > 0.f ? 1.f / lrun[reg] : 0.f;
        #pragma unroll
        for (int hb = 0; hb < 4; ++hb)
            cb[(size_t)(4 * g + reg) * HH + hb * 16 + lc] = O[hb][reg] * inv;
    }
}

// ---------------- Kernel C: branch proj + residual + LN, summed over 6 branches ----------------
__global__ __launch_bounds__(256) void proj_ln_kernel(
        const float* __restrict__ ctx, const float* __restrict__ Wfc,
        const float* __restrict__ x, float* __restrict__ srow) {
    int bs = blockIdx.x;               // b*S + s
    int b = bs >> 9, s_i = bs & (SS - 1);
    int tid = threadIdx.x;             // d

    __shared__ float cx[HH];
    __shared__ float red[4];

    float xv = x[(size_t)bs * DD + tid];
    float acc = 0.f;
    for (int r = 0; r < RR; ++r) {
        if (tid < HH)
            cx[tid] = ctx[(((size_t)b * RR + r) * SS + s_i) * HH + tid];
        __syncthreads();
        const float* W = Wfc + (size_t)r * HH * DD;
        float p = 0.f;
        #pragma unroll
        for (int h = 0; h < HH; ++h) p += cx[h] * W[h * DD + tid];
        p += xv;
        float mean = block_sum256(p, red) * (1.f / 256.f);
        float d0 = p - mean;
        float var = block_sum256(d0 * d0, red) * (1.f / 256.f);
        acc += d0 * rsqrtf(var + 1e-5f);
        __syncthreads();
    }
    srow[(size_t)bs * DD + tid] = acc;
}

// ---------------- Kernel D: FFN + residual + LN ----------------
__global__ __launch_bounds__(256) void ffn_kernel(
        const float* __restrict__ srow, const float* __restrict__ W1,
        const float* __restrict__ W2, float* __restrict__ out) {
    int bs = blockIdx.x;
    int tid = threadIdx.x;

    __shared__ float sr[DD];
    __shared__ float hr[FF];
    __shared__ float red[4];

    float sv = srow[(size_t)bs * DD + tid];
    sr[tid] = sv;
    __syncthreads();
    float a = 0.f;
    #pragma unroll 8
    for (int d = 0; d < DD; ++d) a += sr[d] * W1[d * FF + tid];
    hr[tid] = fmaxf(a, 0.f);
    __syncthreads();
    float o = 0.f;
    #pragma unroll 8
    for (int f = 0; f < FF; ++f) o += hr[f] * W2[f * DD + tid];
    o += sv;
    float mean = block_sum256(o, red) * (1.f / 256.f);
    float d0 = o - mean;
    float var = block_sum256(d0 * d0, red) * (1.f / 256.f);
    out[(size_t)bs * DD + tid] = d0 * rsqrtf(var + 1e-5f);
}

// ---------------- launch ----------------
extern "C" void kernel_launch(void* const* d_in, const int* in_sizes, int n_in,
                              void* d_out, int out_size, void* d_ws, size_t ws_size,
                              hipStream_t stream) {
    const float* x    = (const float*)d_in[0];
    const int*   mask = (const int*)  d_in[1];
    const float* Wq   = (const float*)d_in[2];
    const float* Wk   = (const float*)d_in[3];
    const float* Wv   = (const float*)d_in[4];
    const float* Wfc  = (const float*)d_in[5];
    const float* W1   = (const float*)d_in[6];
    const float* W2   = (const float*)d_in[7];
    float* out = (float*)d_out;

    const size_t QKV = (size_t)BB * RR * SS * HH;   // 6,291,456 elements
    ushort_t* qb = (ushort_t*)d_ws;                 // bf16
    ushort_t* kb = qb + QKV;
    ushort_t* vb = kb + QKV;
    float* ctx  = (float*)(vb + QKV);               // fp32 [B,6,S,64]
    float* srow = ctx + QKV;                        // fp32 [B,S,256]

    const int nrows = BB * RR * SS;                 // 98304
    const int nbs   = BB * SS;                      // 16384

    qkv_kernel     <<<nrows, 192, 0, stream>>>(x, Wq, Wk, Wv,
                        (__hip_bfloat16*)qb, (__hip_bfloat16*)kb, (__hip_bfloat16*)vb);
    attn_mfma_kernel<<<BB * RR * 8, 256, 0, stream>>>(qb, kb, vb, mask, ctx);
    proj_ln_kernel <<<nbs, 256, 0, stream>>>(ctx, Wfc, x, srow);
    ffn_kernel     <<<nbs, 256, 0, stream>>>(srow, W1, W2, out);
}

// Round 3
// 602.153 us; speedup vs baseline: 3.7985x; 1.8344x over previous
//
#include <hip/hip_runtime.h>
#include <hip/hip_bf16.h>

// Sizes (fixed by the reference)
#define BB 32
#define RR 6
#define SS 512
#define DD 256
#define HH 64
#define FF 256

typedef short  short8 __attribute__((ext_vector_type(8)));
typedef short  short4v __attribute__((ext_vector_type(4)));
typedef float  f32x4  __attribute__((ext_vector_type(4)));
typedef unsigned short ushort_t;

// ---------------- block reduction helper (256-thread blocks, wave=64) ----------------
__device__ __forceinline__ float block_sum256(float v, float* red) {
    #pragma unroll
    for (int off = 32; off > 0; off >>= 1) v += __shfl_down(v, off, 64);
    int wid = threadIdx.x >> 6, lane = threadIdx.x & 63;
    if (lane == 0) red[wid] = v;
    __syncthreads();
    if (threadIdx.x == 0) red[0] = red[0] + red[1] + red[2] + red[3];
    __syncthreads();
    float r = red[0];
    __syncthreads();
    return r;
}

__device__ __forceinline__ ushort_t f2bf(float f) {
    __hip_bfloat16 b = __float2bfloat16(f);
    return __builtin_bit_cast(ushort_t, b);
}

// ---------------- convert x -> bf16 ----------------
__global__ __launch_bounds__(256) void convert_x_kernel(
        const float* __restrict__ x, ushort_t* __restrict__ xb) {
    int gid = blockIdx.x * 256 + threadIdx.x;      // 1,048,576 threads, 4 elems each
    const float4* src = (const float4*)x;
    float4 fv = src[gid];
    short4v o;
    o[0] = (short)f2bf(fv.x); o[1] = (short)f2bf(fv.y);
    o[2] = (short)f2bf(fv.z); o[3] = (short)f2bf(fv.w);
    *(short4v*)(xb + (size_t)gid * 4) = o;
}

// ---------------- convert + transpose weights: wT[(r*3+w)*64 + h][d] = W_w[r][d][h] ----------------
__global__ __launch_bounds__(256) void convert_w_kernel(
        const float* __restrict__ Wq, const float* __restrict__ Wk, const float* __restrict__ Wv,
        ushort_t* __restrict__ wT) {
    int gid = blockIdx.x * 256 + threadIdx.x;      // 294,912 total
    int n = gid >> 8, d = gid & 255;
    int r = n / 192, rem = n % 192;
    int which = rem >> 6, h = rem & 63;
    const float* W = which == 0 ? Wq : which == 1 ? Wk : Wv;
    wT[gid] = f2bf(W[(size_t)r * DD * HH + (size_t)d * HH + h]);
}

// ---------------- Kernel A: QKV GEMM via MFMA, no LDS ----------------
// grid 2304 = 8 XCD * (16 rowtiles * 18 colpanels). Block: 256 thr, 4 waves 2x2,
// output tile 128 rows x 64 cols (one (r,which) panel), K=256 in 8 steps of 32.
__global__ __launch_bounds__(256) void qkv_mfma_kernel(
        const ushort_t* __restrict__ xb, const ushort_t* __restrict__ wT,
        ushort_t* __restrict__ q, ushort_t* __restrict__ k, ushort_t* __restrict__ v) {
    int bid = blockIdx.x;
    int id = (bid & 7) * 288 + (bid >> 3);         // XCD-contiguous
    int rt = id / 18, cw = id % 18;                // cw = r*3 + which
    int r = cw / 3, which = cw % 3;

    int tid = threadIdx.x;
    int wv = tid >> 6, l = tid & 63;
    int wr = wv >> 1, wc = wv & 1;
    int g = l >> 4, lc = l & 15;

    const ushort_t* Arow = xb + ((size_t)(rt * 128 + wr * 64 + lc)) * DD + g * 8;
    const ushort_t* Brow = wT + ((size_t)(cw * 64 + wc * 32 + lc)) * DD + g * 8;

    f32x4 acc[4][2] = {};
    #pragma unroll 4
    for (int ks = 0; ks < 8; ++ks) {
        short8 af[4], bf[2];
        #pragma unroll
        for (int m = 0; m < 4; ++m)
            af[m] = *(const short8*)(Arow + (size_t)m * 16 * DD + ks * 32);
        #pragma unroll
        for (int n = 0; n < 2; ++n)
            bf[n] = *(const short8*)(Brow + (size_t)n * 16 * DD + ks * 32);
        #pragma unroll
        for (int m = 0; m < 4; ++m)
            #pragma unroll
            for (int n = 0; n < 2; ++n)
                acc[m][n] = __builtin_amdgcn_mfma_f32_16x16x32_bf16(af[m], bf[n], acc[m][n], 0, 0, 0);
    }

    ushort_t* outb = which == 0 ? q : which == 1 ? k : v;
    #pragma unroll
    for (int m = 0; m < 4; ++m) {
        #pragma unroll
        for (int reg = 0; reg < 4; ++reg) {
            int grow = rt * 128 + wr * 64 + m * 16 + g * 4 + reg;   // row in [0,16384)
            int orow = ((grow >> 9) * RR + r) * SS + (grow & (SS - 1));
            #pragma unroll
            for (int n = 0; n < 2; ++n)
                outb[(size_t)orow * HH + wc * 32 + n * 16 + lc] = f2bf(acc[m][n][reg]);
        }
    }
}

// ---------------- Kernel B: flash MFMA attention ----------------
// grid = 192 br * 8 qtiles = 1536 blocks, 256 threads (4 waves, 16 q-rows each).
__global__ __launch_bounds__(256) void attn_mfma_kernel(
        const ushort_t* __restrict__ q, const ushort_t* __restrict__ k,
        const ushort_t* __restrict__ v, const int* __restrict__ mask,
        float* __restrict__ ctx) {
    int wg = blockIdx.x;
    int id = (wg & 7) * 192 + (wg >> 3);
    int br = id >> 3, qt = id & 7;

    __shared__ ushort_t K_lds[64 * 72];
    __shared__ ushort_t VT_lds[64 * 72];
    __shared__ ushort_t P_lds[4][16 * 72];

    int tid = threadIdx.x;
    int wv = tid >> 6, l = tid & 63;
    int g = l >> 4, lc = l & 15;

    int q0 = qt * 64 + wv * 16;
    const size_t base_kv = (size_t)br * SS * HH;

    short8 qf[2];
    #pragma unroll
    for (int kk = 0; kk < 2; ++kk)
        qf[kk] = *(const short8*)(q + ((size_t)br * SS + q0 + lc) * HH + kk * 32 + g * 8);

    f32x4 O[4] = {{0,0,0,0},{0,0,0,0},{0,0,0,0},{0,0,0,0}};
    float mrun[4] = {-1e9f, -1e9f, -1e9f, -1e9f};
    float lrun[4] = {0.f, 0.f, 0.f, 0.f};

    const int* mb = mask + ((size_t)br * SS + q0) * SS;

    for (int t0 = 0; t0 < SS; t0 += 64) {
        __syncthreads();
        for (int c = tid; c < 512; c += 256) {
            int t = c >> 3, c8 = (c & 7) * 8;
            *(short8*)&K_lds[t * 72 + c8] =
                *(const short8*)(k + base_kv + (size_t)(t0 + t) * HH + c8);
        }
        {
            int h = tid & 63, tseg = tid >> 6;
            #pragma unroll
            for (int j = 0; j < 16; ++j) {
                int t = tseg * 16 + j;
                VT_lds[h * 72 + t] = v[base_kv + (size_t)(t0 + t) * HH + h];
            }
        }
        __syncthreads();

        f32x4 S[4];
        #pragma unroll
        for (int tc = 0; tc < 4; ++tc) {
            f32x4 c = {0, 0, 0, 0};
            #pragma unroll
            for (int kk = 0; kk < 2; ++kk) {
                short8 bf = *(const short8*)&K_lds[(tc * 16 + lc) * 72 + kk * 32 + g * 8];
                c = __builtin_amdgcn_mfma_f32_16x16x32_bf16(qf[kk], bf, c, 0, 0, 0);
            }
            S[tc] = c;
        }

        float tmax[4] = {-1e9f, -1e9f, -1e9f, -1e9f};
        #pragma unroll
        for (int tc = 0; tc < 4; ++tc)
            #pragma unroll
            for (int reg = 0; reg < 4; ++reg) {
                int qrow = 4 * g + reg;
                int mv = mb[(size_t)qrow * SS + t0 + tc * 16 + lc];
                float sv = mv ? -1e9f : S[tc][reg] * 0.125f;
                S[tc][reg] = sv;
                tmax[reg] = fmaxf(tmax[reg], sv);
            }
        #pragma unroll
        for (int reg = 0; reg < 4; ++reg) {
            float tm = tmax[reg];
            tm = fmaxf(tm, __shfl_xor(tm, 1, 64));
            tm = fmaxf(tm, __shfl_xor(tm, 2, 64));
            tm = fmaxf(tm, __shfl_xor(tm, 4, 64));
            tm = fmaxf(tm, __shfl_xor(tm, 8, 64));
            tmax[reg] = tm;
        }
        float psum[4];
        #pragma unroll
        for (int reg = 0; reg < 4; ++reg) {
            float mnew = fmaxf(mrun[reg], tmax[reg]);
            float corr = __expf(mrun[reg] - mnew);
            mrun[reg] = mnew;
            lrun[reg] *= corr;
            O[0][reg] *= corr; O[1][reg] *= corr; O[2][reg] *= corr; O[3][reg] *= corr;
            psum[reg] = 0.f;
        }
        ushort_t* Pw = P_lds[wv];
        #pragma unroll
        for (int tc = 0; tc < 4; ++tc)
            #pragma unroll
            for (int reg = 0; reg < 4; ++reg) {
                float sv = S[tc][reg];
                float p = (sv == -1e9f) ? 0.f : __expf(sv - mrun[reg]);
                psum[reg] += p;
                Pw[(4 * g + reg) * 72 + tc * 16 + lc] = f2bf(p);
            }
        #pragma unroll
        for (int reg = 0; reg < 4; ++reg) {
            float ps = psum[reg];
            ps += __shfl_xor(ps, 1, 64);
            ps += __shfl_xor(ps, 2, 64);
            ps += __shfl_xor(ps, 4, 64);
            ps += __shfl_xor(ps, 8, 64);
            lrun[reg] += ps;
        }
        asm volatile("s_waitcnt lgkmcnt(0)" ::: "memory");

        #pragma unroll
        for (int ts = 0; ts < 2; ++ts) {
            short8 pa = *(const short8*)&Pw[lc * 72 + ts * 32 + g * 8];
            #pragma unroll
            for (int hb = 0; hb < 4; ++hb) {
                short8 vbf = *(const short8*)&VT_lds[(hb * 16 + lc) * 72 + ts * 32 + g * 8];
                O[hb] = __builtin_amdgcn_mfma_f32_16x16x32_bf16(pa, vbf, O[hb], 0, 0, 0);
            }
        }
    }

    float* cb = ctx + ((size_t)br * SS + q0) * HH;
    #pragma unroll
    for (int reg = 0; reg < 4; ++reg) {
        float inv = lrun[reg] > 0.f ? 1.f / lrun[reg] : 0.f;
        #pragma unroll
        for (int hb = 0; hb < 4; ++hb)
            cb[(size_t)(4 * g + reg) * HH + hb * 16 + lc] = O[hb][reg] * inv;
    }
}

// ---------------- Kernel C: branch proj + residual + LN, summed over 6 branches ----------------
__global__ __launch_bounds__(256) void proj_ln_kernel(
        const float* __restrict__ ctx, const float* __restrict__ Wfc,
        const float* __restrict__ x, float* __restrict__ srow) {
    int bs = blockIdx.x;
    int b = bs >> 9, s_i = bs & (SS - 1);
    int tid = threadIdx.x;

    __shared__ float cx[HH];
    __shared__ float red[4];

    float xv = x[(size_t)bs * DD + tid];
    float acc = 0.f;
    for (int r = 0; r < RR; ++r) {
        if (tid < HH)
            cx[tid] = ctx[(((size_t)b * RR + r) * SS + s_i) * HH + tid];
        __syncthreads();
        const float* W = Wfc + (size_t)r * HH * DD;
        float p = 0.f;
        #pragma unroll
        for (int h = 0; h < HH; ++h) p += cx[h] * W[h * DD + tid];
        p += xv;
        float mean = block_sum256(p, red) * (1.f / 256.f);
        float d0 = p - mean;
        float var = block_sum256(d0 * d0, red) * (1.f / 256.f);
        acc += d0 * rsqrtf(var + 1e-5f);
        __syncthreads();
    }
    srow[(size_t)bs * DD + tid] = acc;
}

// ---------------- Kernel D: FFN + residual + LN ----------------
__global__ __launch_bounds__(256) void ffn_kernel(
        const float* __restrict__ srow, const float* __restrict__ W1,
        const float* __restrict__ W2, float* __restrict__ out) {
    int bs = blockIdx.x;
    int tid = threadIdx.x;

    __shared__ float sr[DD];
    __shared__ float hr[FF];
    __shared__ float red[4];

    float sv = srow[(size_t)bs * DD + tid];
    sr[tid] = sv;
    __syncthreads();
    float a = 0.f;
    #pragma unroll 8
    for (int d = 0; d < DD; ++d) a += sr[d] * W1[d * FF + tid];
    hr[tid] = fmaxf(a, 0.f);
    __syncthreads();
    float o = 0.f;
    #pragma unroll 8
    for (int f = 0; f < FF; ++f) o += hr[f] * W2[f * DD + tid];
    o += sv;
    float mean = block_sum256(o, red) * (1.f / 256.f);
    float d0 = o - mean;
    float var = block_sum256(d0 * d0, red) * (1.f / 256.f);
    out[(size_t)bs * DD + tid] = d0 * rsqrtf(var + 1e-5f);
}

// ---------------- launch ----------------
extern "C" void kernel_launch(void* const* d_in, const int* in_sizes, int n_in,
                              void* d_out, int out_size, void* d_ws, size_t ws_size,
                              hipStream_t stream) {
    const float* x    = (const float*)d_in[0];
    const int*   mask = (const int*)  d_in[1];
    const float* Wq   = (const float*)d_in[2];
    const float* Wk   = (const float*)d_in[3];
    const float* Wv   = (const float*)d_in[4];
    const float* Wfc  = (const float*)d_in[5];
    const float* W1   = (const float*)d_in[6];
    const float* W2   = (const float*)d_in[7];
    float* out = (float*)d_out;

    const size_t QKV = (size_t)BB * RR * SS * HH;   // 6,291,456 elements
    ushort_t* qb = (ushort_t*)d_ws;                 // bf16
    ushort_t* kb = qb + QKV;
    ushort_t* vb = kb + QKV;
    float* ctx  = (float*)(vb + QKV);               // fp32 [B,6,S,64]
    float* srow = ctx + QKV;                        // fp32 [B,S,256]
    ushort_t* xb = (ushort_t*)(srow + (size_t)BB * SS * DD);   // bf16 [B*S,256]
    ushort_t* wT = xb + (size_t)BB * SS * DD;                  // bf16 [1152,256]

    const int nbs = BB * SS;                        // 16384

    convert_x_kernel<<<4096, 256, 0, stream>>>(x, xb);
    convert_w_kernel<<<1152, 256, 0, stream>>>(Wq, Wk, Wv, wT);
    qkv_mfma_kernel <<<2304, 256, 0, stream>>>(xb, wT, qb, kb, vb);
    attn_mfma_kernel<<<BB * RR * 8, 256, 0, stream>>>(qb, kb, vb, mask, ctx);
    proj_ln_kernel  <<<nbs, 256, 0, stream>>>(ctx, Wfc, x, srow);
    ffn_kernel      <<<nbs, 256, 0, stream>>>(srow, W1, W2, out);
}

// Round 4
// 382.319 us; speedup vs baseline: 5.9827x; 1.5750x over previous
//
#include <hip/hip_runtime.h>
#include <hip/hip_bf16.h>

// Sizes (fixed by the reference)
#define BB 32
#define RR 6
#define SS 512
#define DD 256
#define HH 64
#define FF 256

typedef short  short8 __attribute__((ext_vector_type(8)));
typedef short  short4v __attribute__((ext_vector_type(4)));
typedef float  f32x4  __attribute__((ext_vector_type(4)));
typedef unsigned short ushort_t;

// ---------------- block reduction helper (256-thread blocks, wave=64) ----------------
__device__ __forceinline__ float block_sum256(float v, float* red) {
    #pragma unroll
    for (int off = 32; off > 0; off >>= 1) v += __shfl_down(v, off, 64);
    int wid = threadIdx.x >> 6, lane = threadIdx.x & 63;
    if (lane == 0) red[wid] = v;
    __syncthreads();
    if (threadIdx.x == 0) red[0] = red[0] + red[1] + red[2] + red[3];
    __syncthreads();
    float r = red[0];
    __syncthreads();
    return r;
}

__device__ __forceinline__ ushort_t f2bf(float f) {
    __hip_bfloat16 b = __float2bfloat16(f);
    return __builtin_bit_cast(ushort_t, b);
}
__device__ __forceinline__ float bf2f(ushort_t u) {
    return __bfloat162float(__builtin_bit_cast(__hip_bfloat16, u));
}

// ---------------- convert x -> bf16 ----------------
__global__ __launch_bounds__(256) void convert_x_kernel(
        const float* __restrict__ x, ushort_t* __restrict__ xb) {
    int gid = blockIdx.x * 256 + threadIdx.x;
    const float4* src = (const float4*)x;
    float4 fv = src[gid];
    short4v o;
    o[0] = (short)f2bf(fv.x); o[1] = (short)f2bf(fv.y);
    o[2] = (short)f2bf(fv.z); o[3] = (short)f2bf(fv.w);
    *(short4v*)(xb + (size_t)gid * 4) = o;
}

// ---------------- convert + transpose QKV weights: wT[(r*3+w)*64 + h][d] ----------------
__global__ __launch_bounds__(256) void convert_w_kernel(
        const float* __restrict__ Wq, const float* __restrict__ Wk, const float* __restrict__ Wv,
        ushort_t* __restrict__ wT) {
    int gid = blockIdx.x * 256 + threadIdx.x;      // 294,912 total
    int n = gid >> 8, d = gid & 255;
    int r = n / 192, rem = n % 192;
    int which = rem >> 6, h = rem & 63;
    const float* W = which == 0 ? Wq : which == 1 ? Wk : Wv;
    wT[gid] = f2bf(W[(size_t)r * DD * HH + (size_t)d * HH + h]);
}

// ---------------- convert + transpose FFN weights ----------------
// w1T[f][d] = W1[d][f];  w2T[d][f] = W2[f][d]
__global__ __launch_bounds__(256) void convert_ffnw_kernel(
        const float* __restrict__ W1, const float* __restrict__ W2,
        ushort_t* __restrict__ w1T, ushort_t* __restrict__ w2T) {
    int gid = blockIdx.x * 256 + threadIdx.x;      // 131072
    if (gid < 65536) {
        int f = gid >> 8, d = gid & 255;
        w1T[gid] = f2bf(W1[(size_t)d * FF + f]);
    } else {
        int gg = gid - 65536;
        int d = gg >> 8, f = gg & 255;
        w2T[gg] = f2bf(W2[(size_t)f * DD + d]);
    }
}

// ---------------- Kernel A: QKV GEMM via MFMA, no LDS ----------------
__global__ __launch_bounds__(256) void qkv_mfma_kernel(
        const ushort_t* __restrict__ xb, const ushort_t* __restrict__ wT,
        ushort_t* __restrict__ q, ushort_t* __restrict__ k, ushort_t* __restrict__ v) {
    int bid = blockIdx.x;
    int id = (bid & 7) * 288 + (bid >> 3);         // XCD-contiguous
    int rt = id / 18, cw = id % 18;                // cw = r*3 + which
    int r = cw / 3, which = cw % 3;

    int tid = threadIdx.x;
    int wv = tid >> 6, l = tid & 63;
    int wr = wv >> 1, wc = wv & 1;
    int g = l >> 4, lc = l & 15;

    const ushort_t* Arow = xb + ((size_t)(rt * 128 + wr * 64 + lc)) * DD + g * 8;
    const ushort_t* Brow = wT + ((size_t)(cw * 64 + wc * 32 + lc)) * DD + g * 8;

    f32x4 acc[4][2] = {};
    #pragma unroll 4
    for (int ks = 0; ks < 8; ++ks) {
        short8 af[4], bf[2];
        #pragma unroll
        for (int m = 0; m < 4; ++m)
            af[m] = *(const short8*)(Arow + (size_t)m * 16 * DD + ks * 32);
        #pragma unroll
        for (int n = 0; n < 2; ++n)
            bf[n] = *(const short8*)(Brow + (size_t)n * 16 * DD + ks * 32);
        #pragma unroll
        for (int m = 0; m < 4; ++m)
            #pragma unroll
            for (int n = 0; n < 2; ++n)
                acc[m][n] = __builtin_amdgcn_mfma_f32_16x16x32_bf16(af[m], bf[n], acc[m][n], 0, 0, 0);
    }

    ushort_t* outb = which == 0 ? q : which == 1 ? k : v;
    #pragma unroll
    for (int m = 0; m < 4; ++m) {
        #pragma unroll
        for (int reg = 0; reg < 4; ++reg) {
            int grow = rt * 128 + wr * 64 + m * 16 + g * 4 + reg;
            int orow = ((grow >> 9) * RR + r) * SS + (grow & (SS - 1));
            #pragma unroll
            for (int n = 0; n < 2; ++n)
                outb[(size_t)orow * HH + wc * 32 + n * 16 + lc] = f2bf(acc[m][n][reg]);
        }
    }
}

// ---------------- Kernel B: flash MFMA attention ----------------
__global__ __launch_bounds__(256) void attn_mfma_kernel(
        const ushort_t* __restrict__ q, const ushort_t* __restrict__ k,
        const ushort_t* __restrict__ v, const int* __restrict__ mask,
        float* __restrict__ ctx) {
    int wg = blockIdx.x;
    int id = (wg & 7) * 192 + (wg >> 3);
    int br = id >> 3, qt = id & 7;

    __shared__ ushort_t K_lds[64 * 72];
    __shared__ ushort_t VT_lds[64 * 72];
    __shared__ ushort_t P_lds[4][16 * 72];

    int tid = threadIdx.x;
    int wv = tid >> 6, l = tid & 63;
    int g = l >> 4, lc = l & 15;

    int q0 = qt * 64 + wv * 16;
    const size_t base_kv = (size_t)br * SS * HH;

    short8 qf[2];
    #pragma unroll
    for (int kk = 0; kk < 2; ++kk)
        qf[kk] = *(const short8*)(q + ((size_t)br * SS + q0 + lc) * HH + kk * 32 + g * 8);

    f32x4 O[4] = {{0,0,0,0},{0,0,0,0},{0,0,0,0},{0,0,0,0}};
    float mrun[4] = {-1e9f, -1e9f, -1e9f, -1e9f};
    float lrun[4] = {0.f, 0.f, 0.f, 0.f};

    const int* mb = mask + ((size_t)br * SS + q0) * SS;

    for (int t0 = 0; t0 < SS; t0 += 64) {
        __syncthreads();
        for (int c = tid; c < 512; c += 256) {
            int t = c >> 3, c8 = (c & 7) * 8;
            *(short8*)&K_lds[t * 72 + c8] =
                *(const short8*)(k + base_kv + (size_t)(t0 + t) * HH + c8);
        }
        {
            int h = tid & 63, tseg = tid >> 6;
            #pragma unroll
            for (int j = 0; j < 16; ++j) {
                int t = tseg * 16 + j;
                VT_lds[h * 72 + t] = v[base_kv + (size_t)(t0 + t) * HH + h];
            }
        }
        __syncthreads();

        f32x4 S[4];
        #pragma unroll
        for (int tc = 0; tc < 4; ++tc) {
            f32x4 c = {0, 0, 0, 0};
            #pragma unroll
            for (int kk = 0; kk < 2; ++kk) {
                short8 bf = *(const short8*)&K_lds[(tc * 16 + lc) * 72 + kk * 32 + g * 8];
                c = __builtin_amdgcn_mfma_f32_16x16x32_bf16(qf[kk], bf, c, 0, 0, 0);
            }
            S[tc] = c;
        }

        float tmax[4] = {-1e9f, -1e9f, -1e9f, -1e9f};
        #pragma unroll
        for (int tc = 0; tc < 4; ++tc)
            #pragma unroll
            for (int reg = 0; reg < 4; ++reg) {
                int qrow = 4 * g + reg;
                int mv = mb[(size_t)qrow * SS + t0 + tc * 16 + lc];
                float sv = mv ? -1e9f : S[tc][reg] * 0.125f;
                S[tc][reg] = sv;
                tmax[reg] = fmaxf(tmax[reg], sv);
            }
        #pragma unroll
        for (int reg = 0; reg < 4; ++reg) {
            float tm = tmax[reg];
            tm = fmaxf(tm, __shfl_xor(tm, 1, 64));
            tm = fmaxf(tm, __shfl_xor(tm, 2, 64));
            tm = fmaxf(tm, __shfl_xor(tm, 4, 64));
            tm = fmaxf(tm, __shfl_xor(tm, 8, 64));
            tmax[reg] = tm;
        }
        float psum[4];
        #pragma unroll
        for (int reg = 0; reg < 4; ++reg) {
            float mnew = fmaxf(mrun[reg], tmax[reg]);
            float corr = __expf(mrun[reg] - mnew);
            mrun[reg] = mnew;
            lrun[reg] *= corr;
            O[0][reg] *= corr; O[1][reg] *= corr; O[2][reg] *= corr; O[3][reg] *= corr;
            psum[reg] = 0.f;
        }
        ushort_t* Pw = P_lds[wv];
        #pragma unroll
        for (int tc = 0; tc < 4; ++tc)
            #pragma unroll
            for (int reg = 0; reg < 4; ++reg) {
                float sv = S[tc][reg];
                float p = (sv == -1e9f) ? 0.f : __expf(sv - mrun[reg]);
                psum[reg] += p;
                Pw[(4 * g + reg) * 72 + tc * 16 + lc] = f2bf(p);
            }
        #pragma unroll
        for (int reg = 0; reg < 4; ++reg) {
            float ps = psum[reg];
            ps += __shfl_xor(ps, 1, 64);
            ps += __shfl_xor(ps, 2, 64);
            ps += __shfl_xor(ps, 4, 64);
            ps += __shfl_xor(ps, 8, 64);
            lrun[reg] += ps;
        }
        asm volatile("s_waitcnt lgkmcnt(0)" ::: "memory");

        #pragma unroll
        for (int ts = 0; ts < 2; ++ts) {
            short8 pa = *(const short8*)&Pw[lc * 72 + ts * 32 + g * 8];
            #pragma unroll
            for (int hb = 0; hb < 4; ++hb) {
                short8 vbf = *(const short8*)&VT_lds[(hb * 16 + lc) * 72 + ts * 32 + g * 8];
                O[hb] = __builtin_amdgcn_mfma_f32_16x16x32_bf16(pa, vbf, O[hb], 0, 0, 0);
            }
        }
    }

    float* cb = ctx + ((size_t)br * SS + q0) * HH;
    #pragma unroll
    for (int reg = 0; reg < 4; ++reg) {
        float inv = lrun[reg] > 0.f ? 1.f / lrun[reg] : 0.f;
        #pragma unroll
        for (int hb = 0; hb < 4; ++hb)
            cb[(size_t)(4 * g + reg) * HH + hb * 16 + lc] = O[hb][reg] * inv;
    }
}

// ---------------- Kernel C: branch proj + residual + LN, summed over 6 branches (bf16 out) ----------------
__global__ __launch_bounds__(256) void proj_ln_kernel(
        const float* __restrict__ ctx, const float* __restrict__ Wfc,
        const float* __restrict__ x, ushort_t* __restrict__ srow_bf) {
    int bs = blockIdx.x;
    int b = bs >> 9, s_i = bs & (SS - 1);
    int tid = threadIdx.x;

    __shared__ float cx[HH];
    __shared__ float red[4];

    float xv = x[(size_t)bs * DD + tid];
    float acc = 0.f;
    for (int r = 0; r < RR; ++r) {
        if (tid < HH)
            cx[tid] = ctx[(((size_t)b * RR + r) * SS + s_i) * HH + tid];
        __syncthreads();
        const float* W = Wfc + (size_t)r * HH * DD;
        float p = 0.f;
        #pragma unroll
        for (int h = 0; h < HH; ++h) p += cx[h] * W[h * DD + tid];
        p += xv;
        float mean = block_sum256(p, red) * (1.f / 256.f);
        float d0 = p - mean;
        float var = block_sum256(d0 * d0, red) * (1.f / 256.f);
        acc += d0 * rsqrtf(var + 1e-5f);
        __syncthreads();
    }
    srow_bf[(size_t)bs * DD + tid] = f2bf(acc);
}

// ---------------- Kernel D: FFN + residual + LN via MFMA ----------------
// grid 512 (rowtiles of 32), 256 thr = 4 waves 2x2: wave = 16 rows x 128 cols.
__global__ __launch_bounds__(256) void ffn_mfma_kernel(
        const ushort_t* __restrict__ srow_bf, const ushort_t* __restrict__ w1T,
        const ushort_t* __restrict__ w2T, float* __restrict__ out) {
    int rt = blockIdx.x;
    int tid = threadIdx.x;
    int wv = tid >> 6, l = tid & 63;
    int wr = wv >> 1, wc = wv & 1;
    int g = l >> 4, lc = l & 15;

    __shared__ ushort_t s_lds[32 * 264];   // stride 264: row step = 132 dwords = 4 banks mod 32
    __shared__ ushort_t h_lds[32 * 264];
    __shared__ float red_s[32][2];
    __shared__ float red_q[32][2];

    // stage s tile (bf16), 16B chunks, coalesced
    for (int c = tid; c < 1024; c += 256) {
        int row = c >> 5, c8 = (c & 31) * 8;
        *(short8*)&s_lds[row * 264 + c8] =
            *(const short8*)(srow_bf + ((size_t)rt * 32 + row) * DD + c8);
    }
    __syncthreads();

    // GEMM1: h = relu(s @ W1)
    f32x4 acc[8] = {};
    #pragma unroll
    for (int ks = 0; ks < 8; ++ks) {
        short8 af = *(const short8*)&s_lds[(wr * 16 + lc) * 264 + ks * 32 + g * 8];
        #pragma unroll
        for (int hb = 0; hb < 8; ++hb) {
            short8 bf = *(const short8*)(w1T + (size_t)(wc * 128 + hb * 16 + lc) * DD + ks * 32 + g * 8);
            acc[hb] = __builtin_amdgcn_mfma_f32_16x16x32_bf16(af, bf, acc[hb], 0, 0, 0);
        }
    }
    #pragma unroll
    for (int hb = 0; hb < 8; ++hb)
        #pragma unroll
        for (int reg = 0; reg < 4; ++reg) {
            int row = wr * 16 + g * 4 + reg;
            int col = wc * 128 + hb * 16 + lc;
            h_lds[row * 264 + col] = f2bf(fmaxf(acc[hb][reg], 0.f));
        }
    __syncthreads();

    // GEMM2: o = h @ W2
    f32x4 acc2[8] = {};
    #pragma unroll
    for (int ks = 0; ks < 8; ++ks) {
        short8 af = *(const short8*)&h_lds[(wr * 16 + lc) * 264 + ks * 32 + g * 8];
        #pragma unroll
        for (int hb = 0; hb < 8; ++hb) {
            short8 bf = *(const short8*)(w2T + (size_t)(wc * 128 + hb * 16 + lc) * FF + ks * 32 + g * 8);
            acc2[hb] = __builtin_amdgcn_mfma_f32_16x16x32_bf16(af, bf, acc2[hb], 0, 0, 0);
        }
    }

    // epilogue: o += s (residual), then LN per row of 256
    float vals[8][4];
    float psum[4] = {0, 0, 0, 0}, psq[4] = {0, 0, 0, 0};
    #pragma unroll
    for (int hb = 0; hb < 8; ++hb)
        #pragma unroll
        for (int reg = 0; reg < 4; ++reg) {
            int row = wr * 16 + g * 4 + reg;
            int col = wc * 128 + hb * 16 + lc;
            float vv = acc2[hb][reg] + bf2f(s_lds[row * 264 + col]);
            vals[hb][reg] = vv;
            psum[reg] += vv;
            psq[reg]  += vv * vv;
        }
    #pragma unroll
    for (int reg = 0; reg < 4; ++reg) {
        #pragma unroll
        for (int off = 1; off <= 8; off <<= 1) {
            psum[reg] += __shfl_xor(psum[reg], off, 64);
            psq[reg]  += __shfl_xor(psq[reg],  off, 64);
        }
    }
    if (lc == 0) {
        #pragma unroll
        for (int reg = 0; reg < 4; ++reg) {
            int row = wr * 16 + g * 4 + reg;
            red_s[row][wc] = psum[reg];
            red_q[row][wc] = psq[reg];
        }
    }
    __syncthreads();
    float mean_r[4], inv_r[4];
    #pragma unroll
    for (int reg = 0; reg < 4; ++reg) {
        int row = wr * 16 + g * 4 + reg;
        float sum = red_s[row][0] + red_s[row][1];
        float sq  = red_q[row][0] + red_q[row][1];
        float mean = sum * (1.f / 256.f);
        float var  = sq * (1.f / 256.f) - mean * mean;
        mean_r[reg] = mean;
        inv_r[reg]  = rsqrtf(var + 1e-5f);
    }
    #pragma unroll
    for (int hb = 0; hb < 8; ++hb)
        #pragma unroll
        for (int reg = 0; reg < 4; ++reg) {
            int row = wr * 16 + g * 4 + reg;
            int col = wc * 128 + hb * 16 + lc;
            out[((size_t)rt * 32 + row) * DD + col] = (vals[hb][reg] - mean_r[reg]) * inv_r[reg];
        }
}

// ---------------- launch ----------------
extern "C" void kernel_launch(void* const* d_in, const int* in_sizes, int n_in,
                              void* d_out, int out_size, void* d_ws, size_t ws_size,
                              hipStream_t stream) {
    const float* x    = (const float*)d_in[0];
    const int*   mask = (const int*)  d_in[1];
    const float* Wq   = (const float*)d_in[2];
    const float* Wk   = (const float*)d_in[3];
    const float* Wv   = (const float*)d_in[4];
    const float* Wfc  = (const float*)d_in[5];
    const float* W1   = (const float*)d_in[6];
    const float* W2   = (const float*)d_in[7];
    float* out = (float*)d_out;

    const size_t QKV = (size_t)BB * RR * SS * HH;   // 6,291,456 elements
    const size_t BSD = (size_t)BB * SS * DD;        // 4,194,304 elements
    ushort_t* qb = (ushort_t*)d_ws;                 // bf16
    ushort_t* kb = qb + QKV;
    ushort_t* vb = kb + QKV;
    float* ctx   = (float*)(vb + QKV);              // fp32 [B,6,S,64]
    ushort_t* srow_bf = (ushort_t*)(ctx + QKV);     // bf16 [B*S,256]
    ushort_t* xb = srow_bf + BSD;                   // bf16 [B*S,256]
    ushort_t* wT = xb + BSD;                        // bf16 [1152,256]
    ushort_t* w1T = wT + (size_t)1152 * 256;        // bf16 [256,256]
    ushort_t* w2T = w1T + 65536;                    // bf16 [256,256]

    const int nbs = BB * SS;                        // 16384

    convert_x_kernel   <<<4096, 256, 0, stream>>>(x, xb);
    convert_w_kernel   <<<1152, 256, 0, stream>>>(Wq, Wk, Wv, wT);
    convert_ffnw_kernel<<<512,  256, 0, stream>>>(W1, W2, w1T, w2T);
    qkv_mfma_kernel    <<<2304, 256, 0, stream>>>(xb, wT, qb, kb, vb);
    attn_mfma_kernel   <<<BB * RR * 8, 256, 0, stream>>>(qb, kb, vb, mask, ctx);
    proj_ln_kernel     <<<nbs, 256, 0, stream>>>(ctx, Wfc, x, srow_bf);
    ffn_mfma_kernel    <<<512, 256, 0, stream>>>(srow_bf, w1T, w2T, out);
}

// Round 5
// 216.301 us; speedup vs baseline: 10.5747x; 1.7675x over previous
//
#include <hip/hip_runtime.h>
#include <hip/hip_bf16.h>

// Sizes (fixed by the reference)
#define BB 32
#define RR 6
#define SS 512
#define DD 256
#define HH 64
#define FF 256

typedef short  short8 __attribute__((ext_vector_type(8)));
typedef short  short4v __attribute__((ext_vector_type(4)));
typedef float  f32x4  __attribute__((ext_vector_type(4)));
typedef unsigned short ushort_t;

__device__ __forceinline__ ushort_t f2bf(float f) {
    __hip_bfloat16 b = __float2bfloat16(f);
    return __builtin_bit_cast(ushort_t, b);
}
__device__ __forceinline__ float bf2f(ushort_t u) {
    return __bfloat162float(__builtin_bit_cast(__hip_bfloat16, u));
}

// ---------------- convert x -> bf16 ----------------
__global__ __launch_bounds__(256) void convert_x_kernel(
        const float* __restrict__ x, ushort_t* __restrict__ xb) {
    int gid = blockIdx.x * 256 + threadIdx.x;
    const float4* src = (const float4*)x;
    float4 fv = src[gid];
    short4v o;
    o[0] = (short)f2bf(fv.x); o[1] = (short)f2bf(fv.y);
    o[2] = (short)f2bf(fv.z); o[3] = (short)f2bf(fv.w);
    *(short4v*)(xb + (size_t)gid * 4) = o;
}

// ---------------- convert + transpose QKV weights: wT[(r*3+w)*64 + h][d] ----------------
__global__ __launch_bounds__(256) void convert_w_kernel(
        const float* __restrict__ Wq, const float* __restrict__ Wk, const float* __restrict__ Wv,
        ushort_t* __restrict__ wT) {
    int gid = blockIdx.x * 256 + threadIdx.x;      // 294,912 total
    int n = gid >> 8, d = gid & 255;
    int r = n / 192, rem = n % 192;
    int which = rem >> 6, h = rem & 63;
    const float* W = which == 0 ? Wq : which == 1 ? Wk : Wv;
    wT[gid] = f2bf(W[(size_t)r * DD * HH + (size_t)d * HH + h]);
}

// ---------------- convert + transpose FFN weights ----------------
__global__ __launch_bounds__(256) void convert_ffnw_kernel(
        const float* __restrict__ W1, const float* __restrict__ W2,
        ushort_t* __restrict__ w1T, ushort_t* __restrict__ w2T) {
    int gid = blockIdx.x * 256 + threadIdx.x;      // 131072
    if (gid < 65536) {
        int f = gid >> 8, d = gid & 255;
        w1T[gid] = f2bf(W1[(size_t)d * FF + f]);
    } else {
        int gg = gid - 65536;
        int d = gg >> 8, f = gg & 255;
        w2T[gg] = f2bf(W2[(size_t)f * DD + d]);
    }
}

// ---------------- convert + transpose Wfc: wfcT[(r*256 + d)][h] = Wfc[r][h][d] ----------------
__global__ __launch_bounds__(256) void convert_wfc_kernel(
        const float* __restrict__ Wfc, ushort_t* __restrict__ wfcT) {
    int gid = blockIdx.x * 256 + threadIdx.x;      // 98304
    int n = gid >> 6, h = gid & 63;                // n = r*256 + d
    int r = n >> 8, d = n & 255;
    wfcT[gid] = f2bf(Wfc[((size_t)r * HH + h) * DD + d]);
}

// ---------------- Kernel A: QKV GEMM via MFMA, no LDS ----------------
__global__ __launch_bounds__(256) void qkv_mfma_kernel(
        const ushort_t* __restrict__ xb, const ushort_t* __restrict__ wT,
        ushort_t* __restrict__ q, ushort_t* __restrict__ k, ushort_t* __restrict__ v) {
    int bid = blockIdx.x;
    int id = (bid & 7) * 288 + (bid >> 3);         // XCD-contiguous
    int rt = id / 18, cw = id % 18;                // cw = r*3 + which
    int r = cw / 3, which = cw % 3;

    int tid = threadIdx.x;
    int wv = tid >> 6, l = tid & 63;
    int wr = wv >> 1, wc = wv & 1;
    int g = l >> 4, lc = l & 15;

    const ushort_t* Arow = xb + ((size_t)(rt * 128 + wr * 64 + lc)) * DD + g * 8;
    const ushort_t* Brow = wT + ((size_t)(cw * 64 + wc * 32 + lc)) * DD + g * 8;

    f32x4 acc[4][2] = {};
    #pragma unroll 4
    for (int ks = 0; ks < 8; ++ks) {
        short8 af[4], bf[2];
        #pragma unroll
        for (int m = 0; m < 4; ++m)
            af[m] = *(const short8*)(Arow + (size_t)m * 16 * DD + ks * 32);
        #pragma unroll
        for (int n = 0; n < 2; ++n)
            bf[n] = *(const short8*)(Brow + (size_t)n * 16 * DD + ks * 32);
        #pragma unroll
        for (int m = 0; m < 4; ++m)
            #pragma unroll
            for (int n = 0; n < 2; ++n)
                acc[m][n] = __builtin_amdgcn_mfma_f32_16x16x32_bf16(af[m], bf[n], acc[m][n], 0, 0, 0);
    }

    ushort_t* outb = which == 0 ? q : which == 1 ? k : v;
    #pragma unroll
    for (int m = 0; m < 4; ++m) {
        #pragma unroll
        for (int reg = 0; reg < 4; ++reg) {
            int grow = rt * 128 + wr * 64 + m * 16 + g * 4 + reg;
            int orow = ((grow >> 9) * RR + r) * SS + (grow & (SS - 1));
            #pragma unroll
            for (int n = 0; n < 2; ++n)
                outb[(size_t)orow * HH + wc * 32 + n * 16 + lc] = f2bf(acc[m][n][reg]);
        }
    }
}

// ---------------- Kernel B: flash MFMA attention (bf16 ctx out) ----------------
__global__ __launch_bounds__(256) void attn_mfma_kernel(
        const ushort_t* __restrict__ q, const ushort_t* __restrict__ k,
        const ushort_t* __restrict__ v, const int* __restrict__ mask,
        ushort_t* __restrict__ ctx) {
    int wg = blockIdx.x;
    int id = (wg & 7) * 192 + (wg >> 3);
    int br = id >> 3, qt = id & 7;

    __shared__ ushort_t K_lds[64 * 72];
    __shared__ ushort_t VT_lds[64 * 72];
    __shared__ ushort_t P_lds[4][16 * 72];

    int tid = threadIdx.x;
    int wv = tid >> 6, l = tid & 63;
    int g = l >> 4, lc = l & 15;

    int q0 = qt * 64 + wv * 16;
    const size_t base_kv = (size_t)br * SS * HH;

    short8 qf[2];
    #pragma unroll
    for (int kk = 0; kk < 2; ++kk)
        qf[kk] = *(const short8*)(q + ((size_t)br * SS + q0 + lc) * HH + kk * 32 + g * 8);

    f32x4 O[4] = {{0,0,0,0},{0,0,0,0},{0,0,0,0},{0,0,0,0}};
    float mrun[4] = {-1e9f, -1e9f, -1e9f, -1e9f};
    float lrun[4] = {0.f, 0.f, 0.f, 0.f};

    const int* mb = mask + ((size_t)br * SS + q0) * SS;

    for (int t0 = 0; t0 < SS; t0 += 64) {
        __syncthreads();
        for (int c = tid; c < 512; c += 256) {
            int t = c >> 3, c8 = (c & 7) * 8;
            *(short8*)&K_lds[t * 72 + c8] =
                *(const short8*)(k + base_kv + (size_t)(t0 + t) * HH + c8);
        }
        {
            int h = tid & 63, tseg = tid >> 6;
            #pragma unroll
            for (int j = 0; j < 16; ++j) {
                int t = tseg * 16 + j;
                VT_lds[h * 72 + t] = v[base_kv + (size_t)(t0 + t) * HH + h];
            }
        }
        __syncthreads();

        f32x4 S[4];
        #pragma unroll
        for (int tc = 0; tc < 4; ++tc) {
            f32x4 c = {0, 0, 0, 0};
            #pragma unroll
            for (int kk = 0; kk < 2; ++kk) {
                short8 bf = *(const short8*)&K_lds[(tc * 16 + lc) * 72 + kk * 32 + g * 8];
                c = __builtin_amdgcn_mfma_f32_16x16x32_bf16(qf[kk], bf, c, 0, 0, 0);
            }
            S[tc] = c;
        }

        float tmax[4] = {-1e9f, -1e9f, -1e9f, -1e9f};
        #pragma unroll
        for (int tc = 0; tc < 4; ++tc)
            #pragma unroll
            for (int reg = 0; reg < 4; ++reg) {
                int qrow = 4 * g + reg;
                int mv = mb[(size_t)qrow * SS + t0 + tc * 16 + lc];
                float sv = mv ? -1e9f : S[tc][reg] * 0.125f;
                S[tc][reg] = sv;
                tmax[reg] = fmaxf(tmax[reg], sv);
            }
        #pragma unroll
        for (int reg = 0; reg < 4; ++reg) {
            float tm = tmax[reg];
            tm = fmaxf(tm, __shfl_xor(tm, 1, 64));
            tm = fmaxf(tm, __shfl_xor(tm, 2, 64));
            tm = fmaxf(tm, __shfl_xor(tm, 4, 64));
            tm = fmaxf(tm, __shfl_xor(tm, 8, 64));
            tmax[reg] = tm;
        }
        float psum[4];
        #pragma unroll
        for (int reg = 0; reg < 4; ++reg) {
            float mnew = fmaxf(mrun[reg], tmax[reg]);
            float corr = __expf(mrun[reg] - mnew);
            mrun[reg] = mnew;
            lrun[reg] *= corr;
            O[0][reg] *= corr; O[1][reg] *= corr; O[2][reg] *= corr; O[3][reg] *= corr;
            psum[reg] = 0.f;
        }
        ushort_t* Pw = P_lds[wv];
        #pragma unroll
        for (int tc = 0; tc < 4; ++tc)
            #pragma unroll
            for (int reg = 0; reg < 4; ++reg) {
                float sv = S[tc][reg];
                float p = (sv == -1e9f) ? 0.f : __expf(sv - mrun[reg]);
                psum[reg] += p;
                Pw[(4 * g + reg) * 72 + tc * 16 + lc] = f2bf(p);
            }
        #pragma unroll
        for (int reg = 0; reg < 4; ++reg) {
            float ps = psum[reg];
            ps += __shfl_xor(ps, 1, 64);
            ps += __shfl_xor(ps, 2, 64);
            ps += __shfl_xor(ps, 4, 64);
            ps += __shfl_xor(ps, 8, 64);
            lrun[reg] += ps;
        }
        asm volatile("s_waitcnt lgkmcnt(0)" ::: "memory");

        #pragma unroll
        for (int ts = 0; ts < 2; ++ts) {
            short8 pa = *(const short8*)&Pw[lc * 72 + ts * 32 + g * 8];
            #pragma unroll
            for (int hb = 0; hb < 4; ++hb) {
                short8 vbf = *(const short8*)&VT_lds[(hb * 16 + lc) * 72 + ts * 32 + g * 8];
                O[hb] = __builtin_amdgcn_mfma_f32_16x16x32_bf16(pa, vbf, O[hb], 0, 0, 0);
            }
        }
    }

    ushort_t* cb = ctx + ((size_t)br * SS + q0) * HH;
    #pragma unroll
    for (int reg = 0; reg < 4; ++reg) {
        float inv = lrun[reg] > 0.f ? 1.f / lrun[reg] : 0.f;
        #pragma unroll
        for (int hb = 0; hb < 4; ++hb)
            cb[(size_t)(4 * g + reg) * HH + hb * 16 + lc] = f2bf(O[hb][reg] * inv);
    }
}

// ---------------- Kernel C: proj + residual + per-branch LN + 6-way sum, via MFMA ----------------
// grid 512 = 8 XCD * 64: block = 32 (b,s) rows x 256 cols. 4 waves 2x2: wave 16 rows x 128 cols.
__global__ __launch_bounds__(256) void proj_ln_mfma_kernel(
        const ushort_t* __restrict__ ctx, const ushort_t* __restrict__ wfcT,
        const float* __restrict__ x, ushort_t* __restrict__ srow_bf) {
    int bid = blockIdx.x;
    int rt = (bid & 7) * 64 + (bid >> 3);          // XCD-contiguous row tiles
    int b = rt >> 4, s0 = (rt & 15) * 32;

    int tid = threadIdx.x;
    int wv = tid >> 6, l = tid & 63;
    int wr = wv >> 1, wc = wv & 1;
    int g = l >> 4, lc = l & 15;

    __shared__ float red_s[32][2];
    __shared__ float red_q[32][2];

    // residual x (fp32), cached across branches: row = wr*16+g*4+reg, col = wc*128+hb*16+lc
    float xres[8][4];
    #pragma unroll
    for (int hb = 0; hb < 8; ++hb)
        #pragma unroll
        for (int reg = 0; reg < 4; ++reg)
            xres[hb][reg] = x[((size_t)b * SS + s0 + wr * 16 + g * 4 + reg) * DD
                              + wc * 128 + hb * 16 + lc];

    float acc_ln[8][4] = {};

    for (int r = 0; r < RR; ++r) {
        // GEMM: [32 rows x 64] @ [64 x 256] -> per wave 16 rows x 128 cols, K=64 in 2 steps
        const ushort_t* Abase = ctx + (((size_t)b * RR + r) * SS + s0 + wr * 16 + lc) * HH + g * 8;
        const ushort_t* Bbase = wfcT + ((size_t)r * 256 + wc * 128 + lc) * HH + g * 8;
        f32x4 acc[8] = {};
        #pragma unroll
        for (int ks = 0; ks < 2; ++ks) {
            short8 af = *(const short8*)(Abase + ks * 32);
            #pragma unroll
            for (int hb = 0; hb < 8; ++hb) {
                short8 bf = *(const short8*)(Bbase + (size_t)hb * 16 * HH + ks * 32);
                acc[hb] = __builtin_amdgcn_mfma_f32_16x16x32_bf16(af, bf, acc[hb], 0, 0, 0);
            }
        }

        // residual + per-row LN stats (row = 256 cols split across wc halves)
        float vals[8][4];
        float psum[4] = {0, 0, 0, 0}, psq[4] = {0, 0, 0, 0};
        #pragma unroll
        for (int hb = 0; hb < 8; ++hb)
            #pragma unroll
            for (int reg = 0; reg < 4; ++reg) {
                float vv = acc[hb][reg] + xres[hb][reg];
                vals[hb][reg] = vv;
                psum[reg] += vv;
                psq[reg]  += vv * vv;
            }
        #pragma unroll
        for (int reg = 0; reg < 4; ++reg) {
            #pragma unroll
            for (int off = 1; off <= 8; off <<= 1) {
                psum[reg] += __shfl_xor(psum[reg], off, 64);
                psq[reg]  += __shfl_xor(psq[reg],  off, 64);
            }
        }
        if (lc == 0) {
            #pragma unroll
            for (int reg = 0; reg < 4; ++reg) {
                int row = wr * 16 + g * 4 + reg;
                red_s[row][wc] = psum[reg];
                red_q[row][wc] = psq[reg];
            }
        }
        __syncthreads();
        float mean_r[4], inv_r[4];
        #pragma unroll
        for (int reg = 0; reg < 4; ++reg) {
            int row = wr * 16 + g * 4 + reg;
            float sum = red_s[row][0] + red_s[row][1];
            float sq  = red_q[row][0] + red_q[row][1];
            float mean = sum * (1.f / 256.f);
            float var  = sq * (1.f / 256.f) - mean * mean;
            mean_r[reg] = mean;
            inv_r[reg]  = rsqrtf(var + 1e-5f);
        }
        #pragma unroll
        for (int hb = 0; hb < 8; ++hb)
            #pragma unroll
            for (int reg = 0; reg < 4; ++reg)
                acc_ln[hb][reg] += (vals[hb][reg] - mean_r[reg]) * inv_r[reg];
        __syncthreads();   // red_s/red_q reuse-safe
    }

    #pragma unroll
    for (int hb = 0; hb < 8; ++hb)
        #pragma unroll
        for (int reg = 0; reg < 4; ++reg) {
            int row = wr * 16 + g * 4 + reg;
            int col = wc * 128 + hb * 16 + lc;
            srow_bf[((size_t)b * SS + s0 + row) * DD + col] = f2bf(acc_ln[hb][reg]);
        }
}

// ---------------- Kernel D: FFN + residual + LN via MFMA ----------------
__global__ __launch_bounds__(256) void ffn_mfma_kernel(
        const ushort_t* __restrict__ srow_bf, const ushort_t* __restrict__ w1T,
        const ushort_t* __restrict__ w2T, float* __restrict__ out) {
    int rt = blockIdx.x;
    int tid = threadIdx.x;
    int wv = tid >> 6, l = tid & 63;
    int wr = wv >> 1, wc = wv & 1;
    int g = l >> 4, lc = l & 15;

    __shared__ ushort_t s_lds[32 * 264];
    __shared__ ushort_t h_lds[32 * 264];
    __shared__ float red_s[32][2];
    __shared__ float red_q[32][2];

    for (int c = tid; c < 1024; c += 256) {
        int row = c >> 5, c8 = (c & 31) * 8;
        *(short8*)&s_lds[row * 264 + c8] =
            *(const short8*)(srow_bf + ((size_t)rt * 32 + row) * DD + c8);
    }
    __syncthreads();

    f32x4 acc[8] = {};
    #pragma unroll
    for (int ks = 0; ks < 8; ++ks) {
        short8 af = *(const short8*)&s_lds[(wr * 16 + lc) * 264 + ks * 32 + g * 8];
        #pragma unroll
        for (int hb = 0; hb < 8; ++hb) {
            short8 bf = *(const short8*)(w1T + (size_t)(wc * 128 + hb * 16 + lc) * DD + ks * 32 + g * 8);
            acc[hb] = __builtin_amdgcn_mfma_f32_16x16x32_bf16(af, bf, acc[hb], 0, 0, 0);
        }
    }
    #pragma unroll
    for (int hb = 0; hb < 8; ++hb)
        #pragma unroll
        for (int reg = 0; reg < 4; ++reg) {
            int row = wr * 16 + g * 4 + reg;
            int col = wc * 128 + hb * 16 + lc;
            h_lds[row * 264 + col] = f2bf(fmaxf(acc[hb][reg], 0.f));
        }
    __syncthreads();

    f32x4 acc2[8] = {};
    #pragma unroll
    for (int ks = 0; ks < 8; ++ks) {
        short8 af = *(const short8*)&h_lds[(wr * 16 + lc) * 264 + ks * 32 + g * 8];
        #pragma unroll
        for (int hb = 0; hb < 8; ++hb) {
            short8 bf = *(const short8*)(w2T + (size_t)(wc * 128 + hb * 16 + lc) * FF + ks * 32 + g * 8);
            acc2[hb] = __builtin_amdgcn_mfma_f32_16x16x32_bf16(af, bf, acc2[hb], 0, 0, 0);
        }
    }

    float vals[8][4];
    float psum[4] = {0, 0, 0, 0}, psq[4] = {0, 0, 0, 0};
    #pragma unroll
    for (int hb = 0; hb < 8; ++hb)
        #pragma unroll
        for (int reg = 0; reg < 4; ++reg) {
            int row = wr * 16 + g * 4 + reg;
            int col = wc * 128 + hb * 16 + lc;
            float vv = acc2[hb][reg] + bf2f(s_lds[row * 264 + col]);
            vals[hb][reg] = vv;
            psum[reg] += vv;
            psq[reg]  += vv * vv;
        }
    #pragma unroll
    for (int reg = 0; reg < 4; ++reg) {
        #pragma unroll
        for (int off = 1; off <= 8; off <<= 1) {
            psum[reg] += __shfl_xor(psum[reg], off, 64);
            psq[reg]  += __shfl_xor(psq[reg],  off, 64);
        }
    }
    if (lc == 0) {
        #pragma unroll
        for (int reg = 0; reg < 4; ++reg) {
            int row = wr * 16 + g * 4 + reg;
            red_s[row][wc] = psum[reg];
            red_q[row][wc] = psq[reg];
        }
    }
    __syncthreads();
    float mean_r[4], inv_r[4];
    #pragma unroll
    for (int reg = 0; reg < 4; ++reg) {
        int row = wr * 16 + g * 4 + reg;
        float sum = red_s[row][0] + red_s[row][1];
        float sq  = red_q[row][0] + red_q[row][1];
        float mean = sum * (1.f / 256.f);
        float var  = sq * (1.f / 256.f) - mean * mean;
        mean_r[reg] = mean;
        inv_r[reg]  = rsqrtf(var + 1e-5f);
    }
    #pragma unroll
    for (int hb = 0; hb < 8; ++hb)
        #pragma unroll
        for (int reg = 0; reg < 4; ++reg) {
            int row = wr * 16 + g * 4 + reg;
            int col = wc * 128 + hb * 16 + lc;
            out[((size_t)rt * 32 + row) * DD + col] = (vals[hb][reg] - mean_r[reg]) * inv_r[reg];
        }
}

// ---------------- launch ----------------
extern "C" void kernel_launch(void* const* d_in, const int* in_sizes, int n_in,
                              void* d_out, int out_size, void* d_ws, size_t ws_size,
                              hipStream_t stream) {
    const float* x    = (const float*)d_in[0];
    const int*   mask = (const int*)  d_in[1];
    const float* Wq   = (const float*)d_in[2];
    const float* Wk   = (const float*)d_in[3];
    const float* Wv   = (const float*)d_in[4];
    const float* Wfc  = (const float*)d_in[5];
    const float* W1   = (const float*)d_in[6];
    const float* W2   = (const float*)d_in[7];
    float* out = (float*)d_out;

    const size_t QKV = (size_t)BB * RR * SS * HH;   // 6,291,456 elements
    const size_t BSD = (size_t)BB * SS * DD;        // 4,194,304 elements
    ushort_t* qb  = (ushort_t*)d_ws;                // bf16
    ushort_t* kb  = qb + QKV;
    ushort_t* vb  = kb + QKV;
    ushort_t* ctx = vb + QKV;                       // bf16 [B,6,S,64]
    ushort_t* srow_bf = ctx + QKV;                  // bf16 [B*S,256]
    ushort_t* xb  = srow_bf + BSD;                  // bf16 [B*S,256]
    ushort_t* wT  = xb + BSD;                       // bf16 [1152,256]
    ushort_t* wfcT = wT + (size_t)1152 * 256;       // bf16 [6*256,64]
    ushort_t* w1T = wfcT + (size_t)RR * 256 * 64;   // bf16 [256,256]
    ushort_t* w2T = w1T + 65536;                    // bf16 [256,256]

    convert_x_kernel   <<<4096, 256, 0, stream>>>(x, xb);
    convert_w_kernel   <<<1152, 256, 0, stream>>>(Wq, Wk, Wv, wT);
    convert_ffnw_kernel<<<512,  256, 0, stream>>>(W1, W2, w1T, w2T);
    convert_wfc_kernel <<<384,  256, 0, stream>>>(Wfc, wfcT);
    qkv_mfma_kernel    <<<2304, 256, 0, stream>>>(xb, wT, qb, kb, vb);
    attn_mfma_kernel   <<<BB * RR * 8, 256, 0, stream>>>(qb, kb, vb, mask, ctx);
    proj_ln_mfma_kernel<<<512, 256, 0, stream>>>(ctx, wfcT, x, srow_bf);
    ffn_mfma_kernel    <<<512, 256, 0, stream>>>(srow_bf, w1T, w2T, out);
}